// Round 3
// baseline (623.216 us; speedup 1.0000x reference)
//
#include <hip/hip_runtime.h>
#include <hip/hip_bf16.h>
#include <stdint.h>

// ---------------------------------------------------------------------------
// Supermask MLP (all fp32 I/O): global top-50% mask over score pool
// [sW1, sb1, sW2, sb2, sW3, sb3], applied in place to [W1, b1, W2, b2, W3, b3],
// then 3 GEMMs (bf16 MFMA compute, fp32 accumulate).
// ---------------------------------------------------------------------------

typedef __bf16 bf16_t;
typedef __bf16 bf16x8 __attribute__((ext_vector_type(8)));
typedef float  f32x4  __attribute__((ext_vector_type(4)));

#define O1 4194304L
#define O2 4198400L
#define O3 20975616L
#define O4 20979712L
#define O5 25174016L
#define N_TOT 25175040L
#define J_RANK 12587520u
#define CAND_CAP 4096

// ws layout (bytes)
#define WS_HIST 0u          // 8192 x uint
#define WS_RES  32768u      // res[0]=bucket, res[1]=below_count, res[2]=need_drop
#define WS_CNT  32784u      // candidate counter
#define WS_CAND 32800u      // 4096 x u64
#define WS_H1   131072u     // 1024x4096 bf16 (8 MB)
#define WS_H2   8519680u    // 1024x4096 bf16 (8 MB)

// monotone fp32-bits -> 32-bit key (ascending key == ascending float)
__device__ __forceinline__ unsigned int mono32(float f) {
    unsigned int u = __float_as_uint(f);
    return (u & 0x80000000u) ? ~u : (u | 0x80000000u);
}

__global__ __launch_bounds__(256) void zero_kernel(unsigned int* p, int n) {
    int i = blockIdx.x * 256 + threadIdx.x;
    if (i < n) p[i] = 0u;
}

__device__ __forceinline__ void seg_lookup(long e,
    const float* s0, const float* s1, const float* s2,
    const float* s3, const float* s4, const float* s5,
    const float** sp, long* off) {
    if (e < O1)      { *sp = s0; *off = e; }
    else if (e < O2) { *sp = s1; *off = e - O1; }
    else if (e < O3) { *sp = s2; *off = e - O2; }
    else if (e < O4) { *sp = s3; *off = e - O3; }
    else if (e < O5) { *sp = s4; *off = e - O4; }
    else             { *sp = s5; *off = e - O5; }
}

__global__ __launch_bounds__(256) void hist_kernel(
    const float* s0, const float* s1, const float* s2,
    const float* s3, const float* s4, const float* s5,
    unsigned int* hist) {
    __shared__ unsigned int lh[8192];
    for (int i = threadIdx.x; i < 8192; i += 256) lh[i] = 0u;
    __syncthreads();
    const long ng = N_TOT / 4;
    for (long g = (long)blockIdx.x * 256 + threadIdx.x; g < ng;
         g += (long)gridDim.x * 256) {
        long e = g * 4;
        const float* sp; long o;
        seg_lookup(e, s0, s1, s2, s3, s4, s5, &sp, &o);
        float4 v = *(const float4*)(sp + o);
        atomicAdd(&lh[mono32(v.x) >> 19], 1u);
        atomicAdd(&lh[mono32(v.y) >> 19], 1u);
        atomicAdd(&lh[mono32(v.z) >> 19], 1u);
        atomicAdd(&lh[mono32(v.w) >> 19], 1u);
    }
    __syncthreads();
    for (int i = threadIdx.x; i < 8192; i += 256) {
        unsigned int c = lh[i];
        if (c) atomicAdd(&hist[i], c);
    }
}

__global__ __launch_bounds__(256) void select_kernel(const unsigned int* hist,
                                                     unsigned int* res) {
    __shared__ unsigned int part[256];
    int tid = threadIdx.x;
    unsigned int s = 0;
    for (int b = tid * 32; b < tid * 32 + 32; ++b) s += hist[b];
    part[tid] = s;
    __syncthreads();
    if (tid == 0) {
        unsigned int acc = 0;
        for (int i = 0; i < 256; ++i) { unsigned int v = part[i]; part[i] = acc; acc += v; }
    }
    __syncthreads();
    unsigned int acc = part[tid];
    for (int b = tid * 32; b < tid * 32 + 32; ++b) {
        unsigned int h = hist[b];
        if (acc <= J_RANK && J_RANK < acc + h) {
            res[0] = (unsigned int)b;   // 13-bit key bucket containing rank j
            res[1] = acc;               // count strictly below bucket
            res[2] = J_RANK - acc;      // # bucket-members (lowest key,idx) to DROP
        }
        acc += h;
    }
}

// Zero weights (in place, fp32) whose key-bucket < threshold bucket; collect
// bucket-equal candidates (key, flat index) for exact stable tie-break.
__global__ __launch_bounds__(256) void mask_apply_kernel(
    const float* s0, const float* s1, const float* s2,
    const float* s3, const float* s4, const float* s5,
    float* w0, float* w1, float* w2, float* w3, float* w4, float* w5,
    const unsigned int* res, unsigned int* cand_cnt, unsigned long long* cand) {
    const unsigned int C = res[0];
    const long ng = N_TOT / 4;
    for (long g = (long)blockIdx.x * 256 + threadIdx.x; g < ng;
         g += (long)gridDim.x * 256) {
        long e = g * 4;
        const float* sp; long o;
        seg_lookup(e, s0, s1, s2, s3, s4, s5, &sp, &o);
        float* wp;
        if (e < O1)      wp = w0;
        else if (e < O2) wp = w1;
        else if (e < O3) wp = w2;
        else if (e < O4) wp = w3;
        else if (e < O5) wp = w4;
        else             wp = w5;
        float4 sv = *(const float4*)(sp + o);
        float4 wv = *(float4*)(wp + o);
#define PROC(comp, ci)                                                         \
        { unsigned int key = mono32(sv.comp); unsigned int kb = key >> 19;     \
          if (kb < C) wv.comp = 0.f;                                           \
          else if (kb == C) {                                                  \
              unsigned int slot = atomicAdd(cand_cnt, 1u);                     \
              if (slot < CAND_CAP)                                             \
                  cand[slot] = (((unsigned long long)key) << 32) |             \
                               (unsigned long long)(unsigned int)(e + ci);     \
          } }
        PROC(x, 0) PROC(y, 1) PROC(z, 2) PROC(w, 3)
#undef PROC
        *(float4*)(wp + o) = wv;
    }
}

// Sort candidates by (key, flat index) ascending; zero the first need_drop —
// exactly reproduces stable argsort's cut inside the threshold bucket.
__global__ __launch_bounds__(256) void finalize_kernel(
    const unsigned int* res, const unsigned int* cand_cnt,
    const unsigned long long* cand,
    float* w0, float* w1, float* w2, float* w3, float* w4, float* w5) {
    __shared__ unsigned long long buf[CAND_CAP];
    int tid = threadIdx.x;
    unsigned int cnt = *cand_cnt; if (cnt > CAND_CAP) cnt = CAND_CAP;
    unsigned int need = res[2];   if (need > cnt) need = cnt;
    for (int i = tid; i < CAND_CAP; i += 256)
        buf[i] = (i < (int)cnt) ? cand[i] : ~0ULL;
    __syncthreads();
    for (int k = 2; k <= CAND_CAP; k <<= 1) {
        for (int j = k >> 1; j > 0; j >>= 1) {
            for (int i = tid; i < CAND_CAP; i += 256) {
                int ixj = i ^ j;
                if (ixj > i) {
                    bool up = (i & k) == 0;
                    unsigned long long a = buf[i], b = buf[ixj];
                    if ((a > b) == up) { buf[i] = b; buf[ixj] = a; }
                }
            }
            __syncthreads();
        }
    }
    for (int i = tid; i < (int)need; i += 256) {
        long idx = (long)(unsigned int)(buf[i] & 0xFFFFFFFFu);
        if (idx < O1)      w0[idx] = 0.f;
        else if (idx < O2) w1[idx - O1] = 0.f;
        else if (idx < O3) w2[idx - O2] = 0.f;
        else if (idx < O4) w3[idx - O3] = 0.f;
        else if (idx < O5) w4[idx - O4] = 0.f;
        else               w5[idx - O5] = 0.f;
    }
}

// ---------------------------------------------------------------------------
// GEMM: C[M,N] = act( A[M,K] @ B[N,K]^T + bias[N] ), sources fp32 or bf16,
// converted to bf16 during LDS staging; MFMA 16x16x32 bf16, fp32 accumulate.
// ---------------------------------------------------------------------------
__device__ __forceinline__ bf16x8 load8(const float* p) {
    float4 a = *(const float4*)p;
    float4 b = *(const float4*)(p + 4);
    bf16x8 r;
    r[0] = (__bf16)a.x; r[1] = (__bf16)a.y; r[2] = (__bf16)a.z; r[3] = (__bf16)a.w;
    r[4] = (__bf16)b.x; r[5] = (__bf16)b.y; r[6] = (__bf16)b.z; r[7] = (__bf16)b.w;
    return r;
}
__device__ __forceinline__ bf16x8 load8(const bf16_t* p) {
    return *(const bf16x8*)p;
}

template <int BM, int BN, bool RELU, typename TA, typename TB, typename TC>
__global__ __launch_bounds__(256) void gemm_bt(
    const TA* __restrict__ A, const TB* __restrict__ B,
    const float* __restrict__ bias, TC* __restrict__ C,
    int M, int N, int K) {
    constexpr int BK = 32;
    constexpr int WM = BM / 2, WN = BN / 2;
    constexpr int TM = WM / 16, TN = WN / 16;
    constexpr int CA = (BM * BK) / 8;   // 8-element chunks in A tile
    constexpr int CB = (BN * BK) / 8;
    __shared__ __align__(16) bf16_t As[BM * BK];
    __shared__ __align__(16) bf16_t Bs[BN * BK];

    const int tid = threadIdx.x;
    const int w = tid >> 6, lane = tid & 63;
    const int quad = lane >> 4, l16 = lane & 15;
    const int wm = (w >> 1) * WM, wn = (w & 1) * WN;
    const int rowBase = blockIdx.y * BM;
    const int colBase = blockIdx.x * BN;

    f32x4 acc[TM][TN] = {};

    const TA* Ab = A + (size_t)rowBase * K;
    const TB* Bb = B + (size_t)colBase * K;

    for (int k0 = 0; k0 < K; k0 += BK) {
        __syncthreads();
#pragma unroll
        for (int c0 = 0; c0 < CA; c0 += 256) {
            int c = c0 + tid;
            int row = c >> 2, kc = c & 3;
            *(bf16x8*)&As[c * 8] = load8(Ab + (size_t)row * K + k0 + kc * 8);
        }
#pragma unroll
        for (int c0 = 0; c0 < CB; c0 += 256) {
            int c = c0 + tid;
            int row = c >> 2, kc = c & 3;
            *(bf16x8*)&Bs[c * 8] = load8(Bb + (size_t)row * K + k0 + kc * 8);
        }
        __syncthreads();
        bf16x8 af[TM], bfr[TN];
#pragma unroll
        for (int i = 0; i < TM; ++i)
            af[i] = *(const bf16x8*)&As[(wm + i * 16 + l16) * BK + quad * 8];
#pragma unroll
        for (int j = 0; j < TN; ++j)
            bfr[j] = *(const bf16x8*)&Bs[(wn + j * 16 + l16) * BK + quad * 8];
#pragma unroll
        for (int i = 0; i < TM; ++i)
#pragma unroll
            for (int j = 0; j < TN; ++j)
                acc[i][j] = __builtin_amdgcn_mfma_f32_16x16x32_bf16(
                    af[i], bfr[j], acc[i][j], 0, 0, 0);
    }

#pragma unroll
    for (int i = 0; i < TM; ++i) {
#pragma unroll
        for (int j = 0; j < TN; ++j) {
            int col = colBase + wn + j * 16 + l16;
            float bv = bias[col];
#pragma unroll
            for (int r = 0; r < 4; ++r) {
                int rowg = rowBase + wm + i * 16 + quad * 4 + r;
                float v = acc[i][j][r] + bv;
                if (RELU) v = v > 0.f ? v : 0.f;
                if constexpr (sizeof(TC) == 4)
                    C[(size_t)rowg * N + col] = v;
                else
                    C[(size_t)rowg * N + col] = (bf16_t)v;
            }
        }
    }
}

extern "C" void kernel_launch(void* const* d_in, const int* in_sizes, int n_in,
                              void* d_out, int out_size, void* d_ws, size_t ws_size,
                              hipStream_t stream) {
    const float* x  = (const float*)d_in[0];
    float* W1 = (float*)d_in[1];
    float* b1 = (float*)d_in[2];
    float* W2 = (float*)d_in[3];
    float* b2 = (float*)d_in[4];
    float* W3 = (float*)d_in[5];
    float* b3 = (float*)d_in[6];
    const float* s0 = (const float*)d_in[7];
    const float* s1 = (const float*)d_in[8];
    const float* s2 = (const float*)d_in[9];
    const float* s3 = (const float*)d_in[10];
    const float* s4 = (const float*)d_in[11];
    const float* s5 = (const float*)d_in[12];

    uint8_t* ws = (uint8_t*)d_ws;
    unsigned int* hist = (unsigned int*)(ws + WS_HIST);
    unsigned int* res  = (unsigned int*)(ws + WS_RES);
    unsigned int* cnt  = (unsigned int*)(ws + WS_CNT);
    unsigned long long* cand = (unsigned long long*)(ws + WS_CAND);
    bf16_t* H1 = (bf16_t*)(ws + WS_H1);
    bf16_t* H2 = (bf16_t*)(ws + WS_H2);
    float* OUT = (float*)d_out;

    zero_kernel<<<33, 256, 0, stream>>>((unsigned int*)ws, 8200);
    hist_kernel<<<2048, 256, 0, stream>>>(s0, s1, s2, s3, s4, s5, hist);
    select_kernel<<<1, 256, 0, stream>>>(hist, res);
    mask_apply_kernel<<<2048, 256, 0, stream>>>(s0, s1, s2, s3, s4, s5,
                                                W1, b1, W2, b2, W3, b3,
                                                res, cnt, cand);
    finalize_kernel<<<1, 256, 0, stream>>>(res, cnt, cand,
                                           W1, b1, W2, b2, W3, b3);
    // L1: H1 = relu(x @ W1^T + b1)   M=1024 N=4096 K=1024
    gemm_bt<128, 128, true, float, float, bf16_t><<<dim3(32, 8), 256, 0, stream>>>(
        x, W1, b1, H1, 1024, 4096, 1024);
    // L2: H2 = relu(H1 @ W2^T + b2)  M=1024 N=4096 K=4096
    gemm_bt<128, 128, true, bf16_t, float, bf16_t><<<dim3(32, 8), 256, 0, stream>>>(
        H1, W2, b2, H2, 1024, 4096, 4096);
    // L3: out = H2 @ W3^T + b3       M=1024 N=1024 K=4096
    gemm_bt<64, 64, false, bf16_t, float, float><<<dim3(16, 16), 256, 0, stream>>>(
        H2, W3, b3, OUT, 1024, 1024, 4096);
}

// Round 4
// 501.952 us; speedup vs baseline: 1.2416x; 1.2416x over previous
//
#include <hip/hip_runtime.h>
#include <hip/hip_bf16.h>
#include <stdint.h>

// ---------------------------------------------------------------------------
// Supermask MLP (all fp32 I/O): global top-50% mask over score pool
// [sW1, sb1, sW2, sb2, sW3, sb3], applied in place to [W1, b1, W2, b2, W3, b3],
// then 3 GEMMs (bf16 MFMA compute, fp32 accumulate).
// ---------------------------------------------------------------------------

typedef __bf16 bf16_t;
typedef __bf16 bf16x8 __attribute__((ext_vector_type(8)));
typedef float  f32x4  __attribute__((ext_vector_type(4)));

#define O1 4194304L
#define O2 4198400L
#define O3 20975616L
#define O4 20979712L
#define O5 25174016L
#define N_TOT 25175040L
#define J_RANK 12587520u
#define CAND_CAP 4096

// ws layout (bytes)
#define WS_HIST 0u          // 8192 x uint
#define WS_RES  32768u      // res[0]=bucket, res[1]=below_count, res[2]=need_drop
#define WS_CNT  32784u      // candidate counter
#define WS_CAND 32800u      // 4096 x u64
#define WS_H1   131072u     // 1024x4096 bf16 (8 MB)
#define WS_H2   8519680u    // 1024x4096 bf16 (8 MB)

// monotone fp32-bits -> 32-bit key (ascending key == ascending float)
__device__ __forceinline__ unsigned int mono32(float f) {
    unsigned int u = __float_as_uint(f);
    return (u & 0x80000000u) ? ~u : (u | 0x80000000u);
}

__global__ __launch_bounds__(256) void zero_kernel(unsigned int* p, int n) {
    int i = blockIdx.x * 256 + threadIdx.x;
    if (i < n) p[i] = 0u;
}

__device__ __forceinline__ void seg_lookup(long e,
    const float* s0, const float* s1, const float* s2,
    const float* s3, const float* s4, const float* s5,
    const float** sp, long* off) {
    if (e < O1)      { *sp = s0; *off = e; }
    else if (e < O2) { *sp = s1; *off = e - O1; }
    else if (e < O3) { *sp = s2; *off = e - O2; }
    else if (e < O4) { *sp = s3; *off = e - O3; }
    else if (e < O5) { *sp = s4; *off = e - O4; }
    else             { *sp = s5; *off = e - O5; }
}

__global__ __launch_bounds__(256) void hist_kernel(
    const float* s0, const float* s1, const float* s2,
    const float* s3, const float* s4, const float* s5,
    unsigned int* hist) {
    __shared__ unsigned int lh[8192];
    for (int i = threadIdx.x; i < 8192; i += 256) lh[i] = 0u;
    __syncthreads();
    const long ng = N_TOT / 4;
    for (long g = (long)blockIdx.x * 256 + threadIdx.x; g < ng;
         g += (long)gridDim.x * 256) {
        long e = g * 4;
        const float* sp; long o;
        seg_lookup(e, s0, s1, s2, s3, s4, s5, &sp, &o);
        float4 v = *(const float4*)(sp + o);
        atomicAdd(&lh[mono32(v.x) >> 19], 1u);
        atomicAdd(&lh[mono32(v.y) >> 19], 1u);
        atomicAdd(&lh[mono32(v.z) >> 19], 1u);
        atomicAdd(&lh[mono32(v.w) >> 19], 1u);
    }
    __syncthreads();
    for (int i = threadIdx.x; i < 8192; i += 256) {
        unsigned int c = lh[i];
        if (c) atomicAdd(&hist[i], c);
    }
}

__global__ __launch_bounds__(256) void select_kernel(const unsigned int* hist,
                                                     unsigned int* res) {
    __shared__ unsigned int part[256];
    int tid = threadIdx.x;
    unsigned int s = 0;
    for (int b = tid * 32; b < tid * 32 + 32; ++b) s += hist[b];
    part[tid] = s;
    __syncthreads();
    if (tid == 0) {
        unsigned int acc = 0;
        for (int i = 0; i < 256; ++i) { unsigned int v = part[i]; part[i] = acc; acc += v; }
    }
    __syncthreads();
    unsigned int acc = part[tid];
    for (int b = tid * 32; b < tid * 32 + 32; ++b) {
        unsigned int h = hist[b];
        if (acc <= J_RANK && J_RANK < acc + h) {
            res[0] = (unsigned int)b;   // 13-bit key bucket containing rank j
            res[1] = acc;               // count strictly below bucket
            res[2] = J_RANK - acc;      // # bucket-members (lowest key,idx) to DROP
        }
        acc += h;
    }
}

// Zero weights (in place, fp32) whose key-bucket < threshold bucket; collect
// bucket-equal candidates (key, flat index) for exact stable tie-break.
__global__ __launch_bounds__(256) void mask_apply_kernel(
    const float* s0, const float* s1, const float* s2,
    const float* s3, const float* s4, const float* s5,
    float* w0, float* w1, float* w2, float* w3, float* w4, float* w5,
    const unsigned int* res, unsigned int* cand_cnt, unsigned long long* cand) {
    const unsigned int C = res[0];
    const long ng = N_TOT / 4;
    for (long g = (long)blockIdx.x * 256 + threadIdx.x; g < ng;
         g += (long)gridDim.x * 256) {
        long e = g * 4;
        const float* sp; long o;
        seg_lookup(e, s0, s1, s2, s3, s4, s5, &sp, &o);
        float* wp;
        if (e < O1)      wp = w0;
        else if (e < O2) wp = w1;
        else if (e < O3) wp = w2;
        else if (e < O4) wp = w3;
        else if (e < O5) wp = w4;
        else             wp = w5;
        float4 sv = *(const float4*)(sp + o);
        float4 wv = *(float4*)(wp + o);
#define PROC(comp, ci)                                                         \
        { unsigned int key = mono32(sv.comp); unsigned int kb = key >> 19;     \
          if (kb < C) wv.comp = 0.f;                                           \
          else if (kb == C) {                                                  \
              unsigned int slot = atomicAdd(cand_cnt, 1u);                     \
              if (slot < CAND_CAP)                                             \
                  cand[slot] = (((unsigned long long)key) << 32) |             \
                               (unsigned long long)(unsigned int)(e + ci);     \
          } }
        PROC(x, 0) PROC(y, 1) PROC(z, 2) PROC(w, 3)
#undef PROC
        *(float4*)(wp + o) = wv;
    }
}

// Exact rank-count tie-break: candidate (key,idx) pairs are unique, so strict
// u64 ordering == stable argsort order. Zero the `need` lowest-ranked.
// All threads scan buf[j] in lockstep -> LDS broadcast reads (free).
__global__ __launch_bounds__(256) void finalize_kernel(
    const unsigned int* res, const unsigned int* cand_cnt,
    const unsigned long long* cand,
    float* w0, float* w1, float* w2, float* w3, float* w4, float* w5) {
    __shared__ unsigned long long buf[CAND_CAP];
    int tid = threadIdx.x;
    unsigned int cnt = *cand_cnt; if (cnt > CAND_CAP) cnt = CAND_CAP;
    unsigned int need = res[2];   if (need > cnt) need = cnt;
    for (int i = tid; i < (int)cnt; i += 256) buf[i] = cand[i];
    __syncthreads();
    for (int i = tid; i < (int)cnt; i += 256) {
        unsigned long long me = buf[i];
        unsigned int rank = 0;
        for (unsigned int j = 0; j < cnt; ++j) rank += (buf[j] < me);
        if (rank < need) {
            long idx = (long)(unsigned int)(me & 0xFFFFFFFFu);
            if (idx < O1)      w0[idx] = 0.f;
            else if (idx < O2) w1[idx - O1] = 0.f;
            else if (idx < O3) w2[idx - O2] = 0.f;
            else if (idx < O4) w3[idx - O3] = 0.f;
            else if (idx < O5) w4[idx - O4] = 0.f;
            else               w5[idx - O5] = 0.f;
        }
    }
}

// ---------------------------------------------------------------------------
// GEMM: C[M,N] = act( A[M,K] @ B[N,K]^T + bias[N] ), sources fp32 or bf16,
// converted to bf16 during LDS staging; MFMA 16x16x32 bf16, fp32 accumulate.
// ---------------------------------------------------------------------------
__device__ __forceinline__ bf16x8 load8(const float* p) {
    float4 a = *(const float4*)p;
    float4 b = *(const float4*)(p + 4);
    bf16x8 r;
    r[0] = (__bf16)a.x; r[1] = (__bf16)a.y; r[2] = (__bf16)a.z; r[3] = (__bf16)a.w;
    r[4] = (__bf16)b.x; r[5] = (__bf16)b.y; r[6] = (__bf16)b.z; r[7] = (__bf16)b.w;
    return r;
}
__device__ __forceinline__ bf16x8 load8(const bf16_t* p) {
    return *(const bf16x8*)p;
}

template <int BM, int BN, bool RELU, typename TA, typename TB, typename TC>
__global__ __launch_bounds__(256) void gemm_bt(
    const TA* __restrict__ A, const TB* __restrict__ B,
    const float* __restrict__ bias, TC* __restrict__ C,
    int M, int N, int K) {
    constexpr int BK = 32;
    constexpr int WM = BM / 2, WN = BN / 2;
    constexpr int TM = WM / 16, TN = WN / 16;
    constexpr int CA = (BM * BK) / 8;   // 8-element chunks in A tile
    constexpr int CB = (BN * BK) / 8;
    __shared__ __align__(16) bf16_t As[BM * BK];
    __shared__ __align__(16) bf16_t Bs[BN * BK];

    const int tid = threadIdx.x;
    const int w = tid >> 6, lane = tid & 63;
    const int quad = lane >> 4, l16 = lane & 15;
    const int wm = (w >> 1) * WM, wn = (w & 1) * WN;
    const int rowBase = blockIdx.y * BM;
    const int colBase = blockIdx.x * BN;

    f32x4 acc[TM][TN] = {};

    const TA* Ab = A + (size_t)rowBase * K;
    const TB* Bb = B + (size_t)colBase * K;

    for (int k0 = 0; k0 < K; k0 += BK) {
        __syncthreads();
#pragma unroll
        for (int c0 = 0; c0 < CA; c0 += 256) {
            int c = c0 + tid;
            int row = c >> 2, kc = c & 3;
            *(bf16x8*)&As[c * 8] = load8(Ab + (size_t)row * K + k0 + kc * 8);
        }
#pragma unroll
        for (int c0 = 0; c0 < CB; c0 += 256) {
            int c = c0 + tid;
            int row = c >> 2, kc = c & 3;
            *(bf16x8*)&Bs[c * 8] = load8(Bb + (size_t)row * K + k0 + kc * 8);
        }
        __syncthreads();
        bf16x8 af[TM], bfr[TN];
#pragma unroll
        for (int i = 0; i < TM; ++i)
            af[i] = *(const bf16x8*)&As[(wm + i * 16 + l16) * BK + quad * 8];
#pragma unroll
        for (int j = 0; j < TN; ++j)
            bfr[j] = *(const bf16x8*)&Bs[(wn + j * 16 + l16) * BK + quad * 8];
#pragma unroll
        for (int i = 0; i < TM; ++i)
#pragma unroll
            for (int j = 0; j < TN; ++j)
                acc[i][j] = __builtin_amdgcn_mfma_f32_16x16x32_bf16(
                    af[i], bfr[j], acc[i][j], 0, 0, 0);
    }

#pragma unroll
    for (int i = 0; i < TM; ++i) {
#pragma unroll
        for (int j = 0; j < TN; ++j) {
            int col = colBase + wn + j * 16 + l16;
            float bv = bias[col];
#pragma unroll
            for (int r = 0; r < 4; ++r) {
                int rowg = rowBase + wm + i * 16 + quad * 4 + r;
                float v = acc[i][j][r] + bv;
                if (RELU) v = v > 0.f ? v : 0.f;
                if constexpr (sizeof(TC) == 4)
                    C[(size_t)rowg * N + col] = v;
                else
                    C[(size_t)rowg * N + col] = (bf16_t)v;
            }
        }
    }
}

extern "C" void kernel_launch(void* const* d_in, const int* in_sizes, int n_in,
                              void* d_out, int out_size, void* d_ws, size_t ws_size,
                              hipStream_t stream) {
    const float* x  = (const float*)d_in[0];
    float* W1 = (float*)d_in[1];
    float* b1 = (float*)d_in[2];
    float* W2 = (float*)d_in[3];
    float* b2 = (float*)d_in[4];
    float* W3 = (float*)d_in[5];
    float* b3 = (float*)d_in[6];
    const float* s0 = (const float*)d_in[7];
    const float* s1 = (const float*)d_in[8];
    const float* s2 = (const float*)d_in[9];
    const float* s3 = (const float*)d_in[10];
    const float* s4 = (const float*)d_in[11];
    const float* s5 = (const float*)d_in[12];

    uint8_t* ws = (uint8_t*)d_ws;
    unsigned int* hist = (unsigned int*)(ws + WS_HIST);
    unsigned int* res  = (unsigned int*)(ws + WS_RES);
    unsigned int* cnt  = (unsigned int*)(ws + WS_CNT);
    unsigned long long* cand = (unsigned long long*)(ws + WS_CAND);
    bf16_t* H1 = (bf16_t*)(ws + WS_H1);
    bf16_t* H2 = (bf16_t*)(ws + WS_H2);
    float* OUT = (float*)d_out;

    zero_kernel<<<33, 256, 0, stream>>>((unsigned int*)ws, 8200);
    hist_kernel<<<2048, 256, 0, stream>>>(s0, s1, s2, s3, s4, s5, hist);
    select_kernel<<<1, 256, 0, stream>>>(hist, res);
    mask_apply_kernel<<<2048, 256, 0, stream>>>(s0, s1, s2, s3, s4, s5,
                                                W1, b1, W2, b2, W3, b3,
                                                res, cnt, cand);
    finalize_kernel<<<1, 256, 0, stream>>>(res, cnt, cand,
                                           W1, b1, W2, b2, W3, b3);
    // L1: H1 = relu(x @ W1^T + b1)   M=1024 N=4096 K=1024
    gemm_bt<128, 128, true, float, float, bf16_t><<<dim3(32, 8), 256, 0, stream>>>(
        x, W1, b1, H1, 1024, 4096, 1024);
    // L2: H2 = relu(H1 @ W2^T + b2)  M=1024 N=4096 K=4096
    gemm_bt<128, 128, true, bf16_t, float, bf16_t><<<dim3(32, 8), 256, 0, stream>>>(
        H1, W2, b2, H2, 1024, 4096, 4096);
    // L3: out = H2 @ W3^T + b3       M=1024 N=1024 K=4096
    gemm_bt<64, 64, false, bf16_t, float, float><<<dim3(16, 16), 256, 0, stream>>>(
        H2, W3, b3, OUT, 1024, 1024, 4096);
}

// Round 5
// 431.202 us; speedup vs baseline: 1.4453x; 1.1641x over previous
//
#include <hip/hip_runtime.h>
#include <hip/hip_bf16.h>
#include <stdint.h>

// ---------------------------------------------------------------------------
// Supermask MLP (all fp32 I/O): global top-50% mask over score pool
// [sW1, sb1, sW2, sb2, sW3, sb3] applied to [W1, b1, W2, b2, W3, b3],
// then 3 GEMMs (bf16 MFMA, fp32 accumulate).
// Fast path (ws_size >= 64.2 MiB): masked weights written as bf16 to ws,
// d_in untouched. Fallback: in-place fp32 masking (round-4 behavior).
// ---------------------------------------------------------------------------

typedef __bf16 bf16_t;
typedef __bf16 bf16x4 __attribute__((ext_vector_type(4)));
typedef __bf16 bf16x8 __attribute__((ext_vector_type(8)));
typedef float  f32x4  __attribute__((ext_vector_type(4)));

#define O1 4194304L
#define O2 4198400L
#define O3 20975616L
#define O4 20979712L
#define O5 25174016L
#define N_TOT 25175040L
#define J_RANK 12587520u
#define CAND_CAP 4096

// ws layout (bytes)
#define WS_HIST 0u
#define WS_RES  32768u
#define WS_CNT  32784u
#define WS_CAND 32800u
// fast path
#define WS_W1B  131072u
#define WS_B1F  8519680u
#define WS_W2B  8536064u
#define WS_B2F  42090496u
#define WS_W3B  42106880u
#define WS_B3F  50495488u
#define WS_H1F  50511872u
#define WS_H2F  58900480u
#define WS_FAST_END 67289088ull
// fallback path
#define WS_H1   131072u
#define WS_H2   8519680u

// LDS bank-conflict swizzle: physical 8-elt chunk for (row, logical chunk)
#define SWZ(row, chunk) ((((chunk) + ((row) >> 1)) & 3))

// monotone fp32-bits -> 32-bit key (ascending key == ascending float)
__device__ __forceinline__ unsigned int mono32(float f) {
    unsigned int u = __float_as_uint(f);
    return (u & 0x80000000u) ? ~u : (u | 0x80000000u);
}

__global__ __launch_bounds__(256) void zero_kernel(unsigned int* p, int n) {
    int i = blockIdx.x * 256 + threadIdx.x;
    if (i < n) p[i] = 0u;
}

__device__ __forceinline__ void seg_lookup(long e,
    const float* s0, const float* s1, const float* s2,
    const float* s3, const float* s4, const float* s5,
    const float** sp, long* off) {
    if (e < O1)      { *sp = s0; *off = e; }
    else if (e < O2) { *sp = s1; *off = e - O1; }
    else if (e < O3) { *sp = s2; *off = e - O2; }
    else if (e < O4) { *sp = s3; *off = e - O3; }
    else if (e < O5) { *sp = s4; *off = e - O4; }
    else             { *sp = s5; *off = e - O5; }
}

__global__ __launch_bounds__(256) void hist_kernel(
    const float* s0, const float* s1, const float* s2,
    const float* s3, const float* s4, const float* s5,
    unsigned int* hist) {
    __shared__ unsigned int lh[8192];
    for (int i = threadIdx.x; i < 8192; i += 256) lh[i] = 0u;
    __syncthreads();
    const long ng = N_TOT / 4;
    for (long g = (long)blockIdx.x * 256 + threadIdx.x; g < ng;
         g += (long)gridDim.x * 256) {
        long e = g * 4;
        const float* sp; long o;
        seg_lookup(e, s0, s1, s2, s3, s4, s5, &sp, &o);
        float4 v = *(const float4*)(sp + o);
        atomicAdd(&lh[mono32(v.x) >> 19], 1u);
        atomicAdd(&lh[mono32(v.y) >> 19], 1u);
        atomicAdd(&lh[mono32(v.z) >> 19], 1u);
        atomicAdd(&lh[mono32(v.w) >> 19], 1u);
    }
    __syncthreads();
    for (int i = threadIdx.x; i < 8192; i += 256) {
        unsigned int c = lh[i];
        if (c) atomicAdd(&hist[i], c);
    }
}

__global__ __launch_bounds__(256) void select_kernel(const unsigned int* hist,
                                                     unsigned int* res) {
    __shared__ unsigned int part[256];
    int tid = threadIdx.x;
    unsigned int s = 0;
    for (int b = tid * 32; b < tid * 32 + 32; ++b) s += hist[b];
    part[tid] = s;
    __syncthreads();
    if (tid == 0) {
        unsigned int acc = 0;
        for (int i = 0; i < 256; ++i) { unsigned int v = part[i]; part[i] = acc; acc += v; }
    }
    __syncthreads();
    unsigned int acc = part[tid];
    for (int b = tid * 32; b < tid * 32 + 32; ++b) {
        unsigned int h = hist[b];
        if (acc <= J_RANK && J_RANK < acc + h) {
            res[0] = (unsigned int)b;
            res[1] = acc;
            res[2] = J_RANK - acc;   // # bucket members (lowest key,idx) to DROP
        }
        acc += h;
    }
}

// ---- fast path: read scores+weights fp32, write masked weights bf16 to ws;
// biases fp32 to ws. Collect threshold-bucket candidates for exact tie-break.
__global__ __launch_bounds__(256) void mask_apply_fast(
    const float* s0, const float* s1, const float* s2,
    const float* s3, const float* s4, const float* s5,
    const float* w0, const float* w1, const float* w2,
    const float* w3, const float* w4, const float* w5,
    bf16_t* W1b, float* b1f, bf16_t* W2b, float* b2f, bf16_t* W3b, float* b3f,
    const unsigned int* res, unsigned int* cand_cnt, unsigned long long* cand) {
    const unsigned int C = res[0];
    const long ng = N_TOT / 4;
    for (long g = (long)blockIdx.x * 256 + threadIdx.x; g < ng;
         g += (long)gridDim.x * 256) {
        long e = g * 4;
        const float* sp; long o;
        seg_lookup(e, s0, s1, s2, s3, s4, s5, &sp, &o);
        const float* wp;
        if (e < O1)      wp = w0;
        else if (e < O2) wp = w1;
        else if (e < O3) wp = w2;
        else if (e < O4) wp = w3;
        else if (e < O5) wp = w4;
        else             wp = w5;
        float4 sv = *(const float4*)(sp + o);
        float4 wv = *(const float4*)(wp + o);
#define PROC(comp, ci)                                                         \
        { unsigned int key = mono32(sv.comp); unsigned int kb = key >> 19;     \
          if (kb < C) wv.comp = 0.f;                                           \
          else if (kb == C) {                                                  \
              unsigned int slot = atomicAdd(cand_cnt, 1u);                     \
              if (slot < CAND_CAP)                                             \
                  cand[slot] = (((unsigned long long)key) << 32) |             \
                               (unsigned long long)(unsigned int)(e + ci);     \
          } }
        PROC(x, 0) PROC(y, 1) PROC(z, 2) PROC(w, 3)
#undef PROC
        if (e < O1) {
            bf16x4 b; b[0]=(__bf16)wv.x; b[1]=(__bf16)wv.y; b[2]=(__bf16)wv.z; b[3]=(__bf16)wv.w;
            *(bf16x4*)(W1b + o) = b;
        } else if (e < O2) {
            *(float4*)(b1f + o) = wv;
        } else if (e < O3) {
            bf16x4 b; b[0]=(__bf16)wv.x; b[1]=(__bf16)wv.y; b[2]=(__bf16)wv.z; b[3]=(__bf16)wv.w;
            *(bf16x4*)(W2b + o) = b;
        } else if (e < O4) {
            *(float4*)(b2f + o) = wv;
        } else if (e < O5) {
            bf16x4 b; b[0]=(__bf16)wv.x; b[1]=(__bf16)wv.y; b[2]=(__bf16)wv.z; b[3]=(__bf16)wv.w;
            *(bf16x4*)(W3b + o) = b;
        } else {
            *(float4*)(b3f + o) = wv;
        }
    }
}

__global__ __launch_bounds__(256) void finalize_fast(
    const unsigned int* res, const unsigned int* cand_cnt,
    const unsigned long long* cand,
    bf16_t* W1b, float* b1f, bf16_t* W2b, float* b2f, bf16_t* W3b, float* b3f) {
    __shared__ unsigned long long buf[CAND_CAP];
    int tid = threadIdx.x;
    unsigned int cnt = *cand_cnt; if (cnt > CAND_CAP) cnt = CAND_CAP;
    unsigned int need = res[2];   if (need > cnt) need = cnt;
    for (int i = tid; i < (int)cnt; i += 256) buf[i] = cand[i];
    __syncthreads();
    for (int i = tid; i < (int)cnt; i += 256) {
        unsigned long long me = buf[i];
        unsigned int rank = 0;
        for (unsigned int j = 0; j < cnt; ++j) rank += (buf[j] < me);
        if (rank < need) {
            long idx = (long)(unsigned int)(me & 0xFFFFFFFFu);
            if (idx < O1)      W1b[idx] = (__bf16)0.f;
            else if (idx < O2) b1f[idx - O1] = 0.f;
            else if (idx < O3) W2b[idx - O2] = (__bf16)0.f;
            else if (idx < O4) b2f[idx - O3] = 0.f;
            else if (idx < O5) W3b[idx - O4] = (__bf16)0.f;
            else               b3f[idx - O5] = 0.f;
        }
    }
}

// ---- fallback path (in-place fp32 masking), as round 4 ----
__global__ __launch_bounds__(256) void mask_apply_kernel(
    const float* s0, const float* s1, const float* s2,
    const float* s3, const float* s4, const float* s5,
    float* w0, float* w1, float* w2, float* w3, float* w4, float* w5,
    const unsigned int* res, unsigned int* cand_cnt, unsigned long long* cand) {
    const unsigned int C = res[0];
    const long ng = N_TOT / 4;
    for (long g = (long)blockIdx.x * 256 + threadIdx.x; g < ng;
         g += (long)gridDim.x * 256) {
        long e = g * 4;
        const float* sp; long o;
        seg_lookup(e, s0, s1, s2, s3, s4, s5, &sp, &o);
        float* wp;
        if (e < O1)      wp = w0;
        else if (e < O2) wp = w1;
        else if (e < O3) wp = w2;
        else if (e < O4) wp = w3;
        else if (e < O5) wp = w4;
        else             wp = w5;
        float4 sv = *(const float4*)(sp + o);
        float4 wv = *(float4*)(wp + o);
#define PROC(comp, ci)                                                         \
        { unsigned int key = mono32(sv.comp); unsigned int kb = key >> 19;     \
          if (kb < C) wv.comp = 0.f;                                           \
          else if (kb == C) {                                                  \
              unsigned int slot = atomicAdd(cand_cnt, 1u);                     \
              if (slot < CAND_CAP)                                             \
                  cand[slot] = (((unsigned long long)key) << 32) |             \
                               (unsigned long long)(unsigned int)(e + ci);     \
          } }
        PROC(x, 0) PROC(y, 1) PROC(z, 2) PROC(w, 3)
#undef PROC
        *(float4*)(wp + o) = wv;
    }
}

__global__ __launch_bounds__(256) void finalize_kernel(
    const unsigned int* res, const unsigned int* cand_cnt,
    const unsigned long long* cand,
    float* w0, float* w1, float* w2, float* w3, float* w4, float* w5) {
    __shared__ unsigned long long buf[CAND_CAP];
    int tid = threadIdx.x;
    unsigned int cnt = *cand_cnt; if (cnt > CAND_CAP) cnt = CAND_CAP;
    unsigned int need = res[2];   if (need > cnt) need = cnt;
    for (int i = tid; i < (int)cnt; i += 256) buf[i] = cand[i];
    __syncthreads();
    for (int i = tid; i < (int)cnt; i += 256) {
        unsigned long long me = buf[i];
        unsigned int rank = 0;
        for (unsigned int j = 0; j < cnt; ++j) rank += (buf[j] < me);
        if (rank < need) {
            long idx = (long)(unsigned int)(me & 0xFFFFFFFFu);
            if (idx < O1)      w0[idx] = 0.f;
            else if (idx < O2) w1[idx - O1] = 0.f;
            else if (idx < O3) w2[idx - O2] = 0.f;
            else if (idx < O4) w3[idx - O3] = 0.f;
            else if (idx < O5) w4[idx - O4] = 0.f;
            else               w5[idx - O5] = 0.f;
        }
    }
}

// ---------------------------------------------------------------------------
// GEMM: C[M,N] = act( A[M,K] @ B[N,K]^T + bias[N] ), fp32/bf16 sources,
// bf16 MFMA 16x16x32, fp32 accumulate. Swizzled LDS (2-way max conflicts).
// ---------------------------------------------------------------------------
__device__ __forceinline__ bf16x8 load8(const float* p) {
    float4 a = *(const float4*)p;
    float4 b = *(const float4*)(p + 4);
    bf16x8 r;
    r[0] = (__bf16)a.x; r[1] = (__bf16)a.y; r[2] = (__bf16)a.z; r[3] = (__bf16)a.w;
    r[4] = (__bf16)b.x; r[5] = (__bf16)b.y; r[6] = (__bf16)b.z; r[7] = (__bf16)b.w;
    return r;
}
__device__ __forceinline__ bf16x8 load8(const bf16_t* p) {
    return *(const bf16x8*)p;
}

template <int BM, int BN, bool RELU, typename TA, typename TB, typename TC>
__global__ __launch_bounds__(256) void gemm_bt(
    const TA* __restrict__ A, const TB* __restrict__ B,
    const float* __restrict__ bias, TC* __restrict__ C,
    int M, int N, int K) {
    constexpr int BK = 32;
    constexpr int WM = BM / 2, WN = BN / 2;
    constexpr int TM = WM / 16, TN = WN / 16;
    constexpr int CA = (BM * BK) / 8;
    constexpr int CB = (BN * BK) / 8;
    __shared__ __align__(16) bf16_t As[BM * BK];
    __shared__ __align__(16) bf16_t Bs[BN * BK];

    const int tid = threadIdx.x;
    const int w = tid >> 6, lane = tid & 63;
    const int quad = lane >> 4, l16 = lane & 15;
    const int wm = (w >> 1) * WM, wn = (w & 1) * WN;
    const int rowBase = blockIdx.y * BM;
    const int colBase = blockIdx.x * BN;

    f32x4 acc[TM][TN] = {};

    const TA* Ab = A + (size_t)rowBase * K;
    const TB* Bb = B + (size_t)colBase * K;

    for (int k0 = 0; k0 < K; k0 += BK) {
        __syncthreads();
#pragma unroll
        for (int c0 = 0; c0 < CA; c0 += 256) {
            int c = c0 + tid;
            int row = c >> 2, kc = c & 3;
            *(bf16x8*)&As[row * BK + SWZ(row, kc) * 8] =
                load8(Ab + (size_t)row * K + k0 + kc * 8);
        }
#pragma unroll
        for (int c0 = 0; c0 < CB; c0 += 256) {
            int c = c0 + tid;
            int row = c >> 2, kc = c & 3;
            *(bf16x8*)&Bs[row * BK + SWZ(row, kc) * 8] =
                load8(Bb + (size_t)row * K + k0 + kc * 8);
        }
        __syncthreads();
        bf16x8 af[TM], bfr[TN];
#pragma unroll
        for (int i = 0; i < TM; ++i) {
            int r = wm + i * 16 + l16;
            af[i] = *(const bf16x8*)&As[r * BK + SWZ(r, quad) * 8];
        }
#pragma unroll
        for (int j = 0; j < TN; ++j) {
            int r = wn + j * 16 + l16;
            bfr[j] = *(const bf16x8*)&Bs[r * BK + SWZ(r, quad) * 8];
        }
#pragma unroll
        for (int i = 0; i < TM; ++i)
#pragma unroll
            for (int j = 0; j < TN; ++j)
                acc[i][j] = __builtin_amdgcn_mfma_f32_16x16x32_bf16(
                    af[i], bfr[j], acc[i][j], 0, 0, 0);
    }

#pragma unroll
    for (int i = 0; i < TM; ++i) {
#pragma unroll
        for (int j = 0; j < TN; ++j) {
            int col = colBase + wn + j * 16 + l16;
            float bv = bias[col];
#pragma unroll
            for (int r = 0; r < 4; ++r) {
                int rowg = rowBase + wm + i * 16 + quad * 4 + r;
                float v = acc[i][j][r] + bv;
                if (RELU) v = v > 0.f ? v : 0.f;
                if constexpr (sizeof(TC) == 4)
                    C[(size_t)rowg * N + col] = v;
                else
                    C[(size_t)rowg * N + col] = (bf16_t)v;
            }
        }
    }
}

extern "C" void kernel_launch(void* const* d_in, const int* in_sizes, int n_in,
                              void* d_out, int out_size, void* d_ws, size_t ws_size,
                              hipStream_t stream) {
    const float* x  = (const float*)d_in[0];
    float* W1 = (float*)d_in[1];
    float* b1 = (float*)d_in[2];
    float* W2 = (float*)d_in[3];
    float* b2 = (float*)d_in[4];
    float* W3 = (float*)d_in[5];
    float* b3 = (float*)d_in[6];
    const float* s0 = (const float*)d_in[7];
    const float* s1 = (const float*)d_in[8];
    const float* s2 = (const float*)d_in[9];
    const float* s3 = (const float*)d_in[10];
    const float* s4 = (const float*)d_in[11];
    const float* s5 = (const float*)d_in[12];

    uint8_t* ws = (uint8_t*)d_ws;
    unsigned int* hist = (unsigned int*)(ws + WS_HIST);
    unsigned int* res  = (unsigned int*)(ws + WS_RES);
    unsigned int* cnt  = (unsigned int*)(ws + WS_CNT);
    unsigned long long* cand = (unsigned long long*)(ws + WS_CAND);
    float* OUT = (float*)d_out;

    zero_kernel<<<33, 256, 0, stream>>>((unsigned int*)ws, 8200);
    hist_kernel<<<2048, 256, 0, stream>>>(s0, s1, s2, s3, s4, s5, hist);
    select_kernel<<<1, 256, 0, stream>>>(hist, res);

    if (ws_size >= WS_FAST_END) {
        bf16_t* W1b = (bf16_t*)(ws + WS_W1B);
        float*  b1f = (float*)(ws + WS_B1F);
        bf16_t* W2b = (bf16_t*)(ws + WS_W2B);
        float*  b2f = (float*)(ws + WS_B2F);
        bf16_t* W3b = (bf16_t*)(ws + WS_W3B);
        float*  b3f = (float*)(ws + WS_B3F);
        bf16_t* H1  = (bf16_t*)(ws + WS_H1F);
        bf16_t* H2  = (bf16_t*)(ws + WS_H2F);
        mask_apply_fast<<<2048, 256, 0, stream>>>(
            s0, s1, s2, s3, s4, s5, x ? (const float*)d_in[1] : W1, b1, W2, b2, W3, b3,
            W1b, b1f, W2b, b2f, W3b, b3f, res, cnt, cand);
        finalize_fast<<<1, 256, 0, stream>>>(res, cnt, cand,
                                             W1b, b1f, W2b, b2f, W3b, b3f);
        gemm_bt<64, 128, true, float, bf16_t, bf16_t>
            <<<dim3(32, 16), 256, 0, stream>>>(x, W1b, b1f, H1, 1024, 4096, 1024);
        gemm_bt<64, 128, true, bf16_t, bf16_t, bf16_t>
            <<<dim3(32, 16), 256, 0, stream>>>(H1, W2b, b2f, H2, 1024, 4096, 4096);
        gemm_bt<64, 64, false, bf16_t, bf16_t, float>
            <<<dim3(16, 16), 256, 0, stream>>>(H2, W3b, b3f, OUT, 1024, 1024, 4096);
    } else {
        bf16_t* H1 = (bf16_t*)(ws + WS_H1);
        bf16_t* H2 = (bf16_t*)(ws + WS_H2);
        mask_apply_kernel<<<2048, 256, 0, stream>>>(s0, s1, s2, s3, s4, s5,
                                                    W1, b1, W2, b2, W3, b3,
                                                    res, cnt, cand);
        finalize_kernel<<<1, 256, 0, stream>>>(res, cnt, cand,
                                               W1, b1, W2, b2, W3, b3);
        gemm_bt<64, 128, true, float, float, bf16_t>
            <<<dim3(32, 16), 256, 0, stream>>>(x, W1, b1, H1, 1024, 4096, 1024);
        gemm_bt<64, 128, true, bf16_t, float, bf16_t>
            <<<dim3(32, 16), 256, 0, stream>>>(H1, W2, b2, H2, 1024, 4096, 4096);
        gemm_bt<64, 64, false, bf16_t, float, float>
            <<<dim3(16, 16), 256, 0, stream>>>(H2, W3, b3, OUT, 1024, 1024, 4096);
    }
}